// Round 5
// baseline (270.139 us; speedup 1.0000x reference)
//
#include <hip/hip_runtime.h>
#include <hip/hip_fp16.h>

#define NXK 2048
#define NYK 2048
#define NC  (NXK - 1)   // 2047 cells per dim

// ---------------- build v3: 4 cells/thread, float4 loads + shfl for 5th stencil point ----------------
// rec[cell] = 16 halfs: [f00,f01,f10,f11, gx00..gx11, gy00..gy11, gxy00..gxy11]
// gx = fx*dx, gy = fy*dy, gxy = fxy*dx*dy (premultiplied; raw fx ~ O(1e4) would
// lose fp16 accuracy, fx*dx ~ O(1) is safe).
// Round-3 lesson: NO break inside the unrolled loop (break blocked unrolling ->
// dynamic local-array indexing -> scratch spill -> +20us). Guard-only predication.
__global__ __launch_bounds__(256) void build_kernel(
    const float* __restrict__ xk, const float* __restrict__ yk,
    const float* __restrict__ f,  const float* __restrict__ fx,
    const float* __restrict__ fy, const float* __restrict__ fxy,
    __half* __restrict__ rec)
{
    int lane = threadIdx.x & 63;
    int tid  = blockIdx.x * 256 + threadIdx.x;   // 0..511 per row (2 blocks)
    int j0   = tid * 4;
    int i    = blockIdx.y;
    if (j0 >= NC) return;                        // j0 <= 2044; all 512 threads/row active

    size_t base = (size_t)i * NYK + j0;
    float dx = xk[i + 1] - xk[i];

    // aligned float4 loads: points j0..j0+3 of both rows of all 4 arrays + yk
    float fa[5], fb[5], xa[5], xb[5], ya[5], yb[5], za[5], zb[5], yv[5];
    *(float4*)fa = *(const float4*)(f   + base);
    *(float4*)fb = *(const float4*)(f   + base + NYK);
    *(float4*)xa = *(const float4*)(fx  + base);
    *(float4*)xb = *(const float4*)(fx  + base + NYK);
    *(float4*)ya = *(const float4*)(fy  + base);
    *(float4*)yb = *(const float4*)(fy  + base + NYK);
    *(float4*)za = *(const float4*)(fxy + base);
    *(float4*)zb = *(const float4*)(fxy + base + NYK);
    *(float4*)yv = *(const float4*)(yk + j0);

    // 5th stencil point (j0+4) = neighbor lane's element 0, via shfl_down.
    // Lane 63 (wave boundary) does a predicated scalar load instead.
    fa[4] = __shfl_down(fa[0], 1);
    fb[4] = __shfl_down(fb[0], 1);
    xa[4] = __shfl_down(xa[0], 1);
    xb[4] = __shfl_down(xb[0], 1);
    ya[4] = __shfl_down(ya[0], 1);
    yb[4] = __shfl_down(yb[0], 1);
    za[4] = __shfl_down(za[0], 1);
    zb[4] = __shfl_down(zb[0], 1);
    yv[4] = __shfl_down(yv[0], 1);
    if (lane == 63 && j0 + 4 < NYK) {
        fa[4] = f[base + 4];         fb[4] = f[base + NYK + 4];
        xa[4] = fx[base + 4];        xb[4] = fx[base + NYK + 4];
        ya[4] = fy[base + 4];        yb[4] = fy[base + NYK + 4];
        za[4] = fxy[base + 4];       zb[4] = fxy[base + NYK + 4];
        yv[4] = yk[j0 + 4];
    }
    // (j0==2044: point 2048 OOB -> garbage 5th, used only by invalid cell 2047)

    __half* recp = rec + ((size_t)i * NC + j0) * 16;

    #pragma unroll
    for (int k = 0; k < 4; ++k) {
        bool valid = (j0 + k < NC);
        float dy  = yv[k + 1] - yv[k];
        float dxy = dx * dy;

        union { __half h[16]; float4 v[2]; } r;
        r.h[0]  = __float2half(fa[k]);
        r.h[1]  = __float2half(fa[k + 1]);
        r.h[2]  = __float2half(fb[k]);
        r.h[3]  = __float2half(fb[k + 1]);

        r.h[4]  = __float2half(xa[k] * dx);
        r.h[5]  = __float2half(xa[k + 1] * dx);
        r.h[6]  = __float2half(xb[k] * dx);
        r.h[7]  = __float2half(xb[k + 1] * dx);

        r.h[8]  = __float2half(ya[k] * dy);
        r.h[9]  = __float2half(ya[k + 1] * dy);
        r.h[10] = __float2half(yb[k] * dy);
        r.h[11] = __float2half(yb[k + 1] * dy);

        r.h[12] = __float2half(za[k] * dxy);
        r.h[13] = __float2half(za[k + 1] * dxy);
        r.h[14] = __float2half(zb[k] * dxy);
        r.h[15] = __float2half(zb[k + 1] * dxy);

        if (valid) {
            float4* outp = reinterpret_cast<float4*>(recp + (size_t)k * 16);
            outp[0] = r.v[0];
            outp[1] = r.v[1];
        }
    }
}

// ---------------- gather (round-2 exact, proven 90.5 us): one 32 B record per query ----------------
__global__ __launch_bounds__(256) void gather_kernel(
    const float* __restrict__ xq, const float* __restrict__ yq,
    const float* __restrict__ xk, const float* __restrict__ yk,
    const __half* __restrict__ rec,
    float* __restrict__ out, int nq)
{
    int q = blockIdx.x * blockDim.x + threadIdx.x;
    if (q >= nq) return;

    float xv = xq[q];
    float yv = yq[q];

    int il = (int)floorf(xv * (float)(NXK - 1));
    il = min(max(il, 0), NXK - 2);
    while (il < NXK - 2 && xv >= xk[il + 1]) ++il;
    while (il > 0 && xv < xk[il]) --il;

    int jl = (int)floorf(yv * (float)(NYK - 1));
    jl = min(max(jl, 0), NYK - 2);
    while (jl < NYK - 2 && yv >= yk[jl + 1]) ++jl;
    while (jl > 0 && yv < yk[jl]) --jl;

    float x0 = xk[il], x1 = xk[il + 1];
    float dx = x1 - x0;
    float tx = (xv - x0) * ((dx == 0.0f) ? 0.0f : 1.0f / dx);

    float y0 = yk[jl], y1 = yk[jl + 1];
    float dy = y1 - y0;
    float ty = (yv - y0) * ((dy == 0.0f) ? 0.0f : 1.0f / dy);

    // t-powers through interpax's A_CUBIC (note A[3,3] = -1)
    float u0 = 1.0f + tx * tx * (2.0f * tx - 3.0f);
    float u1 = tx * tx * (3.0f - 2.0f * tx);
    float u2 = tx * (1.0f + tx * (tx - 2.0f));
    float u3 = -tx * tx * (1.0f + tx);

    float v0 = 1.0f + ty * ty * (2.0f * ty - 3.0f);
    float v1 = ty * ty * (3.0f - 2.0f * ty);
    float v2 = ty * (1.0f + ty * (ty - 2.0f));
    float v3 = -ty * ty * (1.0f + ty);

    size_t cell = (size_t)il * NC + jl;
    const float4* rp = reinterpret_cast<const float4*>(rec) + cell * 2;
    union { float4 v[2]; __half2 h2[8]; } r;
    r.v[0] = rp[0];
    r.v[1] = rp[1];

    float2 a, b;
    a = __half22float2(r.h2[0]); b = __half22float2(r.h2[1]);
    float sf   = u0 * a.x + u2 * a.y + u1 * b.x + u3 * b.y;
    a = __half22float2(r.h2[2]); b = __half22float2(r.h2[3]);
    float sgx  = u0 * a.x + u2 * a.y + u1 * b.x + u3 * b.y;
    a = __half22float2(r.h2[4]); b = __half22float2(r.h2[5]);
    float sgy  = u0 * a.x + u2 * a.y + u1 * b.x + u3 * b.y;
    a = __half22float2(r.h2[6]); b = __half22float2(r.h2[7]);
    float sgxy = u0 * a.x + u2 * a.y + u1 * b.x + u3 * b.y;

    out[q] = v0 * sf + v1 * sgx + v2 * sgy + v3 * sgxy;
}

// ---------------- fallback (direct gather, used only if ws too small) ----------------
__global__ __launch_bounds__(256) void interp2d_direct(
    const float* __restrict__ xq, const float* __restrict__ yq,
    const float* __restrict__ xk, const float* __restrict__ yk,
    const float* __restrict__ f,  const float* __restrict__ fx,
    const float* __restrict__ fy, const float* __restrict__ fxy,
    float* __restrict__ out, int nq)
{
    int q = blockIdx.x * blockDim.x + threadIdx.x;
    if (q >= nq) return;

    float xv = xq[q];
    float yv = yq[q];

    int il = (int)floorf(xv * (float)(NXK - 1));
    il = min(max(il, 0), NXK - 2);
    while (il < NXK - 2 && xv >= xk[il + 1]) ++il;
    while (il > 0 && xv < xk[il]) --il;

    int jl = (int)floorf(yv * (float)(NYK - 1));
    jl = min(max(jl, 0), NYK - 2);
    while (jl < NYK - 2 && yv >= yk[jl + 1]) ++jl;
    while (jl > 0 && yv < yk[jl]) --jl;

    float x0 = xk[il], x1 = xk[il + 1];
    float dx = x1 - x0;
    float tx = (xv - x0) * ((dx == 0.0f) ? 0.0f : 1.0f / dx);
    float y0 = yk[jl], y1 = yk[jl + 1];
    float dy = y1 - y0;
    float ty = (yv - y0) * ((dy == 0.0f) ? 0.0f : 1.0f / dy);

    float u0 = 1.0f + tx * tx * (2.0f * tx - 3.0f);
    float u1 = tx * tx * (3.0f - 2.0f * tx);
    float u2 = tx * (1.0f + tx * (tx - 2.0f));
    float u3 = -tx * tx * (1.0f + tx);
    float v0 = 1.0f + ty * ty * (2.0f * ty - 3.0f);
    float v1 = ty * ty * (3.0f - 2.0f * ty);
    float v2 = ty * (1.0f + ty * (ty - 2.0f));
    float v3 = -ty * ty * (1.0f + ty);

    long base = (long)il * NYK + jl;
    const float* p = f + base;
    float sf   = u0 * p[0] + u2 * p[1] + u1 * p[NYK] + u3 * p[NYK + 1];
    p = fx + base;
    float sfx  = u0 * p[0] + u2 * p[1] + u1 * p[NYK] + u3 * p[NYK + 1];
    p = fy + base;
    float sfy  = u0 * p[0] + u2 * p[1] + u1 * p[NYK] + u3 * p[NYK + 1];
    p = fxy + base;
    float sfxy = u0 * p[0] + u2 * p[1] + u1 * p[NYK] + u3 * p[NYK + 1];

    out[q] = v0 * sf + v1 * (sfx * dx) + v2 * (sfy * dy) + v3 * (sfxy * (dx * dy));
}

extern "C" void kernel_launch(void* const* d_in, const int* in_sizes, int n_in,
                              void* d_out, int out_size, void* d_ws, size_t ws_size,
                              hipStream_t stream) {
    const float* xq  = (const float*)d_in[0];
    const float* yq  = (const float*)d_in[1];
    const float* xk  = (const float*)d_in[2];
    const float* yk  = (const float*)d_in[3];
    const float* f   = (const float*)d_in[4];
    const float* fx  = (const float*)d_in[5];
    const float* fy  = (const float*)d_in[6];
    const float* fxy = (const float*)d_in[7];
    float* out = (float*)d_out;

    int nq = in_sizes[0];
    const size_t rec_bytes = (size_t)NC * NC * 16 * sizeof(__half);  // ~134 MB

    if (ws_size >= rec_bytes) {
        __half* rec = (__half*)d_ws;
        // 4 cells/thread along j: 512 threads per row = 2 blocks of 256
        dim3 bgrid((NC + 256 * 4 - 1) / (256 * 4), NC);
        build_kernel<<<bgrid, 256, 0, stream>>>(xk, yk, f, fx, fy, fxy, rec);
        int grid = (nq + 255) / 256;
        gather_kernel<<<grid, 256, 0, stream>>>(xq, yq, xk, yk, rec, out, nq);
    } else {
        int grid = (nq + 255) / 256;
        interp2d_direct<<<grid, 256, 0, stream>>>(xq, yq, xk, yk, f, fx, fy, fxy, out, nq);
    }
}

// Round 6
// 254.710 us; speedup vs baseline: 1.0606x; 1.0606x over previous
//
#include <hip/hip_runtime.h>
#include <hip/hip_fp16.h>

#define NXK 2048
#define NYK 2048
#define NC  (NXK - 1)   // 2047 cells per dim

// ---------------- build: per-cell packed fp16 Hermite record (32 B) ----------------
// rec[cell] = 16 halfs: [f00,f01,f10,f11, gx00..gx11, gy00..gy11, gxy00..gxy11]
// where gx = fx*dx, gy = fy*dy, gxy = fxy*dx*dy  (premultiplied at build time;
// raw fx ~ O(1e4) would lose fp16 accuracy, fx*dx ~ O(1) is safe).
// NOTE (rounds 3/5): 4-cells/thread variants (float4 stencil loads, shfl) both
// REGRESSED ~20 µs vs this naive 1-cell/thread version. Adjacent threads' scalar
// stencil loads hit the same L1 lines and latency is hidden by the 16k-block
// grid; traffic was never the binding constraint. Keep this version.
__global__ __launch_bounds__(256) void build_kernel(
    const float* __restrict__ xk, const float* __restrict__ yk,
    const float* __restrict__ f,  const float* __restrict__ fx,
    const float* __restrict__ fy, const float* __restrict__ fxy,
    __half* __restrict__ rec)
{
    int j = blockIdx.x * blockDim.x + threadIdx.x;
    int i = blockIdx.y;
    if (j >= NC) return;

    size_t base = (size_t)i * NYK + j;
    float dx = xk[i + 1] - xk[i];
    float dy = yk[j + 1] - yk[j];
    float dxy = dx * dy;

    union { __half h[16]; float4 v[2]; } r;

    r.h[0]  = __float2half(f[base]);
    r.h[1]  = __float2half(f[base + 1]);
    r.h[2]  = __float2half(f[base + NYK]);
    r.h[3]  = __float2half(f[base + NYK + 1]);

    r.h[4]  = __float2half(fx[base] * dx);
    r.h[5]  = __float2half(fx[base + 1] * dx);
    r.h[6]  = __float2half(fx[base + NYK] * dx);
    r.h[7]  = __float2half(fx[base + NYK + 1] * dx);

    r.h[8]  = __float2half(fy[base] * dy);
    r.h[9]  = __float2half(fy[base + 1] * dy);
    r.h[10] = __float2half(fy[base + NYK] * dy);
    r.h[11] = __float2half(fy[base + NYK + 1] * dy);

    r.h[12] = __float2half(fxy[base] * dxy);
    r.h[13] = __float2half(fxy[base + 1] * dxy);
    r.h[14] = __float2half(fxy[base + NYK] * dxy);
    r.h[15] = __float2half(fxy[base + NYK + 1] * dxy);

    float4* outp = reinterpret_cast<float4*>(rec + ((size_t)i * NC + j) * 16);
    outp[0] = r.v[0];
    outp[1] = r.v[1];
}

// ---------------- gather: one 32 B record (one 64 B line) per query ----------------
// NOTE (rounds 3/4): MLP=2 and MLP=4 per-thread variants did NOT beat this
// (91.3 / 99.6 µs vs 90.2 µs). FETCH is at the 1-line/query structural floor;
// the ~3.1 TB/s random-line service rate is the operative ceiling.
__global__ __launch_bounds__(256) void gather_kernel(
    const float* __restrict__ xq, const float* __restrict__ yq,
    const float* __restrict__ xk, const float* __restrict__ yk,
    const __half* __restrict__ rec,
    float* __restrict__ out, int nq)
{
    int q = blockIdx.x * blockDim.x + threadIdx.x;
    if (q >= nq) return;

    float xv = xq[q];
    float yv = yq[q];

    int il = (int)floorf(xv * (float)(NXK - 1));
    il = min(max(il, 0), NXK - 2);
    while (il < NXK - 2 && xv >= xk[il + 1]) ++il;
    while (il > 0 && xv < xk[il]) --il;

    int jl = (int)floorf(yv * (float)(NYK - 1));
    jl = min(max(jl, 0), NYK - 2);
    while (jl < NYK - 2 && yv >= yk[jl + 1]) ++jl;
    while (jl > 0 && yv < yk[jl]) --jl;

    float x0 = xk[il], x1 = xk[il + 1];
    float dx = x1 - x0;
    float tx = (xv - x0) * ((dx == 0.0f) ? 0.0f : 1.0f / dx);

    float y0 = yk[jl], y1 = yk[jl + 1];
    float dy = y1 - y0;
    float ty = (yv - y0) * ((dy == 0.0f) ? 0.0f : 1.0f / dy);

    // t-powers through interpax's A_CUBIC (note A[3,3] = -1)
    float u0 = 1.0f + tx * tx * (2.0f * tx - 3.0f);
    float u1 = tx * tx * (3.0f - 2.0f * tx);
    float u2 = tx * (1.0f + tx * (tx - 2.0f));
    float u3 = -tx * tx * (1.0f + tx);

    float v0 = 1.0f + ty * ty * (2.0f * ty - 3.0f);
    float v1 = ty * ty * (3.0f - 2.0f * ty);
    float v2 = ty * (1.0f + ty * (ty - 2.0f));
    float v3 = -ty * ty * (1.0f + ty);

    size_t cell = (size_t)il * NC + jl;
    const float4* rp = reinterpret_cast<const float4*>(rec) + cell * 2;
    union { float4 v[2]; __half2 h2[8]; } r;
    r.v[0] = rp[0];
    r.v[1] = rp[1];

    // h2[0]=(f00,f01) h2[1]=(f10,f11) h2[2]=(gx00,gx01) h2[3]=(gx10,gx11)
    // h2[4]=(gy00,gy01) h2[5]=(gy10,gy11) h2[6]=(gxy00,gxy01) h2[7]=(gxy10,gxy11)
    float2 a, b;
    a = __half22float2(r.h2[0]); b = __half22float2(r.h2[1]);
    float sf   = u0 * a.x + u2 * a.y + u1 * b.x + u3 * b.y;
    a = __half22float2(r.h2[2]); b = __half22float2(r.h2[3]);
    float sgx  = u0 * a.x + u2 * a.y + u1 * b.x + u3 * b.y;
    a = __half22float2(r.h2[4]); b = __half22float2(r.h2[5]);
    float sgy  = u0 * a.x + u2 * a.y + u1 * b.x + u3 * b.y;
    a = __half22float2(r.h2[6]); b = __half22float2(r.h2[7]);
    float sgxy = u0 * a.x + u2 * a.y + u1 * b.x + u3 * b.y;

    out[q] = v0 * sf + v1 * sgx + v2 * sgy + v3 * sgxy;
}

// ---------------- fallback (direct gather, used only if ws too small) ----------------
__global__ __launch_bounds__(256) void interp2d_direct(
    const float* __restrict__ xq, const float* __restrict__ yq,
    const float* __restrict__ xk, const float* __restrict__ yk,
    const float* __restrict__ f,  const float* __restrict__ fx,
    const float* __restrict__ fy, const float* __restrict__ fxy,
    float* __restrict__ out, int nq)
{
    int q = blockIdx.x * blockDim.x + threadIdx.x;
    if (q >= nq) return;

    float xv = xq[q];
    float yv = yq[q];

    int il = (int)floorf(xv * (float)(NXK - 1));
    il = min(max(il, 0), NXK - 2);
    while (il < NXK - 2 && xv >= xk[il + 1]) ++il;
    while (il > 0 && xv < xk[il]) --il;

    int jl = (int)floorf(yv * (float)(NYK - 1));
    jl = min(max(jl, 0), NYK - 2);
    while (jl < NYK - 2 && yv >= yk[jl + 1]) ++jl;
    while (jl > 0 && yv < yk[jl]) --jl;

    float x0 = xk[il], x1 = xk[il + 1];
    float dx = x1 - x0;
    float tx = (xv - x0) * ((dx == 0.0f) ? 0.0f : 1.0f / dx);
    float y0 = yk[jl], y1 = yk[jl + 1];
    float dy = y1 - y0;
    float ty = (yv - y0) * ((dy == 0.0f) ? 0.0f : 1.0f / dy);

    float u0 = 1.0f + tx * tx * (2.0f * tx - 3.0f);
    float u1 = tx * tx * (3.0f - 2.0f * tx);
    float u2 = tx * (1.0f + tx * (tx - 2.0f));
    float u3 = -tx * tx * (1.0f + tx);
    float v0 = 1.0f + ty * ty * (2.0f * ty - 3.0f);
    float v1 = ty * ty * (3.0f - 2.0f * ty);
    float v2 = ty * (1.0f + ty * (ty - 2.0f));
    float v3 = -ty * ty * (1.0f + ty);

    long base = (long)il * NYK + jl;
    const float* p = f + base;
    float sf   = u0 * p[0] + u2 * p[1] + u1 * p[NYK] + u3 * p[NYK + 1];
    p = fx + base;
    float sfx  = u0 * p[0] + u2 * p[1] + u1 * p[NYK] + u3 * p[NYK + 1];
    p = fy + base;
    float sfy  = u0 * p[0] + u2 * p[1] + u1 * p[NYK] + u3 * p[NYK + 1];
    p = fxy + base;
    float sfxy = u0 * p[0] + u2 * p[1] + u1 * p[NYK] + u3 * p[NYK + 1];

    out[q] = v0 * sf + v1 * (sfx * dx) + v2 * (sfy * dy) + v3 * (sfxy * (dx * dy));
}

extern "C" void kernel_launch(void* const* d_in, const int* in_sizes, int n_in,
                              void* d_out, int out_size, void* d_ws, size_t ws_size,
                              hipStream_t stream) {
    const float* xq  = (const float*)d_in[0];
    const float* yq  = (const float*)d_in[1];
    const float* xk  = (const float*)d_in[2];
    const float* yk  = (const float*)d_in[3];
    const float* f   = (const float*)d_in[4];
    const float* fx  = (const float*)d_in[5];
    const float* fy  = (const float*)d_in[6];
    const float* fxy = (const float*)d_in[7];
    float* out = (float*)d_out;

    int nq = in_sizes[0];
    const size_t rec_bytes = (size_t)NC * NC * 16 * sizeof(__half);  // ~134 MB

    if (ws_size >= rec_bytes) {
        __half* rec = (__half*)d_ws;
        dim3 bgrid((NC + 255) / 256, NC);
        build_kernel<<<bgrid, 256, 0, stream>>>(xk, yk, f, fx, fy, fxy, rec);
        int grid = (nq + 255) / 256;
        gather_kernel<<<grid, 256, 0, stream>>>(xq, yq, xk, yk, rec, out, nq);
    } else {
        int grid = (nq + 255) / 256;
        interp2d_direct<<<grid, 255 + 1, 0, stream>>>(xq, yq, xk, yk, f, fx, fy, fxy, out, nq);
    }
}